// Round 5
// baseline (409.943 us; speedup 1.0000x reference)
//
#include <hip/hip_runtime.h>

// SelfInteraction on MI355X.
// R4: circular-buffer B prefetch (depth 4/2, no rotation movs), PSTR=130 odd-stride
// LDS planes + plane skew (bank-conflict-free), 32x32x16 MFMA, fused cb channel.

#define C 128
#define NBATCH 8192

typedef _Float16 f16;
typedef _Float16 f16x8 __attribute__((ext_vector_type(8)));
typedef float f32x16 __attribute__((ext_vector_type(16)));

// ws layout:
// [0, 12MB)  : 3 f16 weight streams (ss, vv*inv_sqrt3, comb=Wsv+Wvs^T), each 2,097,152 f16
//              frag order [h2][vb4][u128][nt2][kt2][lane64][j8]
//                <-> W[u][vb*32+kt*16+(l>>5)*8+j][h*64+nt*32+(l&31)]
// [12MB,32MB): raw channel sums f32 [5][8192][128]  (ss, vv_scaled, cb0, cb1, cb2)
#define WSTREAM_F16_PER_C (2*4*128*2*2*64*8)   // 2,097,152 f16 = 4MB
#define NSTREAM 3
#define RAW_OFF_BYTES ((size_t)NSTREAM*WSTREAM_F16_PER_C*2)  // 12 MB
#define PSTR 130               // 65 dwords/row: odd -> 1-bank shift per z-row
#define PLSZ (64*PSTR + 8)     // plane stride (f16): +8 f16 = 4-dword skew between planes

__device__ __forceinline__ f16x8 splat8(f16 v) { return (f16x8){v, v, v, v, v, v, v, v}; }
union U16x8 { uint4 u; f16x8 h; };
__device__ __forceinline__ f16x8 as_h8(uint4 v) { U16x8 x; x.u = v; return x.h; }
__device__ __forceinline__ f32x16 mfma32(f16x8 a, f16x8 b, f32x16 c) {
    return __builtin_amdgcn_mfma_f32_32x32x16_f16(a, b, c, 0, 0, 0);
}

// ---------------- weight prep ----------------
__global__ __launch_bounds__(256) void prep_weights(
        const float* __restrict__ Wss, const float* __restrict__ Wvv,
        const float* __restrict__ Wsv, const float* __restrict__ Wvs,
        f16* __restrict__ out) {
    __shared__ float lds[128 * 130];
    int c = blockIdx.x >> 7;
    int u = blockIdx.x & 127;
    if (c == 2) {
        for (int i = threadIdx.x; i < 16384; i += 256) {
            int v = i >> 7, w = i & 127;
            lds[v * 130 + w] = Wsv[(size_t)u * 16384 + i] + Wvs[(size_t)v * 16384 + u * 128 + w];
        }
    } else {
        const float* src = (c == 0 ? Wss : Wvv) + (size_t)u * 16384;
        float sc = (c == 0) ? 1.0f : 0.57735026918962576f;
        for (int i = threadIdx.x; i < 16384; i += 256) {
            int v = i >> 7, w = i & 127;
            lds[v * 130 + w] = sc * src[i];
        }
    }
    __syncthreads();
    f16* dst = out + (size_t)c * WSTREAM_F16_PER_C;
    for (int pos = threadIdx.x; pos < 2048; pos += 256) {
        int hh = pos >> 10, vb = (pos >> 8) & 3, nt = (pos >> 7) & 1, kt = (pos >> 6) & 1;
        int l = pos & 63;
        int v0 = vb * 32 + kt * 16 + ((l >> 5) << 3);
        int w = hh * 64 + nt * 32 + (l & 31);
        f16x8 vals;
#pragma unroll
        for (int j = 0; j < 8; ++j) vals[j] = (f16)lds[(v0 + j) * 130 + w];
        size_t off = (((((size_t)(hh * 4 + vb) * 128 + u) * 2 + nt) * 2 + kt) * 64 + l) * 8;
        *(f16x8*)(dst + off) = vals;
    }
}

// 32x32 C/D tile write: row=(reg&3)+8*(reg>>2)+4*lk, col=l31
__device__ __forceinline__ void writeT32(float* __restrict__ raw, int c, int zb, int mtBase,
        int h, int ntOff, int l31, int lk, const f32x16& a, bool st) {
#pragma unroll
    for (int reg = 0; reg < 16; ++reg) {
        int row = (reg & 3) + 8 * (reg >> 2) + 4 * lk;
        int z = zb * 64 + mtBase + row;
        int ww = h * 64 + ntOff + l31;
        float* p = &raw[((size_t)c * NBATCH + z) * 128 + ww];
        if (st) *p = a[reg]; else *p += a[reg];
    }
}

// ---------------- main fused GEMM kernel ----------------
// grid 256: zb = bid>>1 (64-row z-tile), h = bid&1 (XCD-affine). 1024 thr = 16 waves.
// Phase1: wave = (ch, nt, vb): ch 0=ss 1=vv; M=64 N=32 K-quarter(vb).
// Phase2: wave = (mh, vb, nt): fused cb, 3 k per B-load; M=32 N=32 K-quarter.
__global__ __launch_bounds__(1024, 4) void si_main(
        const float* __restrict__ x, const f16* __restrict__ wstream,
        float* __restrict__ raw) {
    __shared__ f16 xp[4 * PLSZ];   // [plane][z][v], plane 0=x0, 1..3=x1k, skewed planes

    int zb = blockIdx.x >> 1;
    int h = blockIdx.x & 1;
    int tid = threadIdx.x;

    for (int i = tid; i < 64 * 512; i += 1024) {
        int z = i >> 9, col = i & 511;
        f16 fv = (f16)x[(size_t)(zb * 64 + z) * 512 + col];
        if (col < 128) {
            xp[z * PSTR + col] = fv;
        } else {
            int cc = col - 128;
            int v = cc / 3, k = cc - v * 3;
            xp[(1 + k) * PLSZ + z * PSTR + v] = fv;
        }
    }
    __syncthreads();

    int lane = tid & 63, w = tid >> 6;
    int l31 = lane & 31, lk = lane >> 5;
    const f16* xp0 = xp;
    const f16* xp1 = xp + PLSZ;
    const f16* xp2 = xp + 2 * PLSZ;
    const f16* xp3 = xp + 3 * PLSZ;

    // ================= phase 1: ss + vv =================
    int ch = w >> 3, nt1 = (w >> 2) & 1, vb1 = w & 3;
    f32x16 acc1[2] = {};
    {
        const uint4* bl = (const uint4*)(wstream + (size_t)ch * WSTREAM_F16_PER_C
                          + (size_t)h * (WSTREAM_F16_PER_C / 2))
                          + (size_t)vb1 * 32768 + nt1 * 128 + lane;

        if (ch == 0) {
            f16x8 vva[2][2];
#pragma unroll
            for (int mt = 0; mt < 2; ++mt)
#pragma unroll
                for (int kt = 0; kt < 2; ++kt)
                    vva[mt][kt] = *(const f16x8*)&xp0[(mt * 32 + l31) * PSTR
                                                     + vb1 * 32 + kt * 16 + lk * 8];
            uint4 B[4][2];
#pragma unroll
            for (int s = 0; s < 4; ++s)
#pragma unroll
                for (int kt = 0; kt < 2; ++kt) B[s][kt] = bl[s * 256 + kt * 64];

            for (int g = 0; g < 32; ++g) {
#pragma unroll
                for (int s = 0; s < 4; ++s) {
                    int uu = g * 4 + s;
                    f16x8 sp0 = splat8(xp0[l31 * PSTR + uu]);
                    f16x8 sp1 = splat8(xp0[(32 + l31) * PSTR + uu]);
                    acc1[0] = mfma32(sp0 * vva[0][0], as_h8(B[s][0]), acc1[0]);
                    acc1[0] = mfma32(sp0 * vva[0][1], as_h8(B[s][1]), acc1[0]);
                    acc1[1] = mfma32(sp1 * vva[1][0], as_h8(B[s][0]), acc1[1]);
                    acc1[1] = mfma32(sp1 * vva[1][1], as_h8(B[s][1]), acc1[1]);
                    int tp = (uu + 4) & 127;
#pragma unroll
                    for (int kt = 0; kt < 2; ++kt) B[s][kt] = bl[tp * 256 + kt * 64];
                }
            }
        } else {
            f16x8 vva[3][2][2];
#pragma unroll
            for (int p = 0; p < 3; ++p)
#pragma unroll
                for (int mt = 0; mt < 2; ++mt)
#pragma unroll
                    for (int kt = 0; kt < 2; ++kt)
                        vva[p][mt][kt] = *(const f16x8*)&xp[(1 + p) * PLSZ
                                            + (mt * 32 + l31) * PSTR
                                            + vb1 * 32 + kt * 16 + lk * 8];
            uint4 B[2][2];
#pragma unroll
            for (int s = 0; s < 2; ++s)
#pragma unroll
                for (int kt = 0; kt < 2; ++kt) B[s][kt] = bl[s * 256 + kt * 64];

            for (int g = 0; g < 64; ++g) {
#pragma unroll
                for (int s = 0; s < 2; ++s) {
                    int uu = g * 2 + s;
                    f16x8 sp00 = splat8(xp1[l31 * PSTR + uu]);
                    f16x8 sp01 = splat8(xp2[l31 * PSTR + uu]);
                    f16x8 sp02 = splat8(xp3[l31 * PSTR + uu]);
                    f16x8 sp10 = splat8(xp1[(32 + l31) * PSTR + uu]);
                    f16x8 sp11 = splat8(xp2[(32 + l31) * PSTR + uu]);
                    f16x8 sp12 = splat8(xp3[(32 + l31) * PSTR + uu]);
                    f16x8 A00 = sp00 * vva[0][0][0] + sp01 * vva[1][0][0] + sp02 * vva[2][0][0];
                    f16x8 A01 = sp00 * vva[0][0][1] + sp01 * vva[1][0][1] + sp02 * vva[2][0][1];
                    f16x8 A10 = sp10 * vva[0][1][0] + sp11 * vva[1][1][0] + sp12 * vva[2][1][0];
                    f16x8 A11 = sp10 * vva[0][1][1] + sp11 * vva[1][1][1] + sp12 * vva[2][1][1];
                    acc1[0] = mfma32(A00, as_h8(B[s][0]), acc1[0]);
                    acc1[0] = mfma32(A01, as_h8(B[s][1]), acc1[0]);
                    acc1[1] = mfma32(A10, as_h8(B[s][0]), acc1[1]);
                    acc1[1] = mfma32(A11, as_h8(B[s][1]), acc1[1]);
                    int tp = (uu + 2) & 127;
#pragma unroll
                    for (int kt = 0; kt < 2; ++kt) B[s][kt] = bl[tp * 256 + kt * 64];
                }
            }
        }
    }
    // phase1 reduce: 4 rounds; wave vb1==r writes its (ch, nt) tile
#pragma unroll
    for (int r = 0; r < 4; ++r) {
        __threadfence_block();
        __syncthreads();
        if (vb1 == r) {
            writeT32(raw, ch, zb, 0,  h, nt1 * 32, l31, lk, acc1[0], r == 0);
            writeT32(raw, ch, zb, 32, h, nt1 * 32, l31, lk, acc1[1], r == 0);
        }
    }

    // ================= phase 2: fused cb (3 k per B-load) =================
    int mh = w >> 3, vb2 = (w >> 1) & 3, nt2 = w & 1;
    f32x16 acc2[3] = {};
    {
        f16x8 vvb[3][2];
#pragma unroll
        for (int p = 0; p < 3; ++p)
#pragma unroll
            for (int kt = 0; kt < 2; ++kt)
                vvb[p][kt] = *(const f16x8*)&xp[(1 + p) * PLSZ + (mh * 32 + l31) * PSTR
                                               + vb2 * 32 + kt * 16 + lk * 8];
        const uint4* bl = (const uint4*)(wstream + (size_t)2 * WSTREAM_F16_PER_C
                          + (size_t)h * (WSTREAM_F16_PER_C / 2))
                          + (size_t)vb2 * 32768 + nt2 * 128 + lane;
        uint4 B[4][2];
#pragma unroll
        for (int s = 0; s < 4; ++s)
#pragma unroll
            for (int kt = 0; kt < 2; ++kt) B[s][kt] = bl[s * 256 + kt * 64];

        for (int g = 0; g < 32; ++g) {
#pragma unroll
            for (int s = 0; s < 4; ++s) {
                int uu = g * 4 + s;
                f16x8 sp = splat8(xp0[(mh * 32 + l31) * PSTR + uu]);
                acc2[0] = mfma32(sp * vvb[0][0], as_h8(B[s][0]), acc2[0]);
                acc2[0] = mfma32(sp * vvb[0][1], as_h8(B[s][1]), acc2[0]);
                acc2[1] = mfma32(sp * vvb[1][0], as_h8(B[s][0]), acc2[1]);
                acc2[1] = mfma32(sp * vvb[1][1], as_h8(B[s][1]), acc2[1]);
                acc2[2] = mfma32(sp * vvb[2][0], as_h8(B[s][0]), acc2[2]);
                acc2[2] = mfma32(sp * vvb[2][1], as_h8(B[s][1]), acc2[2]);
                int tp = (uu + 4) & 127;
#pragma unroll
                for (int kt = 0; kt < 2; ++kt) B[s][kt] = bl[tp * 256 + kt * 64];
            }
        }
    }
    // phase2 reduce: 4 rounds; wave writes tile k=(vb2-r)&3 (k<3) at (mh, nt2)
#pragma unroll
    for (int r = 0; r < 4; ++r) {
        __threadfence_block();
        __syncthreads();
        int k = (vb2 - r) & 3;
        if (k == 0)      writeT32(raw, 2, zb, mh * 32, h, nt2 * 32, l31, lk, acc2[0], r == 0);
        else if (k == 1) writeT32(raw, 3, zb, mh * 32, h, nt2 * 32, l31, lk, acc2[1], r == 0);
        else if (k == 2) writeT32(raw, 4, zb, mh * 32, h, nt2 * 32, l31, lk, acc2[2], r == 0);
    }
}

// ---------------- finalize ----------------
__global__ __launch_bounds__(64) void si_finalize(const float* __restrict__ raw,
                                                  float* __restrict__ out) {
    const float PW0 = 0.0055242717280199f;   // 1/sqrt(2*128*128) == pw1/sqrt(3)
    int z = blockIdx.x;
    int t = threadIdx.x;
    const size_t CS = (size_t)NBATCH * 128;
    const float* r0 = raw + (size_t)z * 128;

    float y0A = PW0 * (r0[t] + r0[CS + t]);
    float y0B = PW0 * (r0[t + 64] + r0[CS + t + 64]);
    float s1 = y0A + y0B, s2 = y0A * y0A + y0B * y0B;
    for (int o = 32; o; o >>= 1) {
        s1 += __shfl_xor(s1, o);
        s2 += __shfl_xor(s2, o);
    }
    float mean = s1 * (1.0f / 128.0f);
    float var = (s2 - 128.0f * mean * mean) * (1.0f / 127.0f);
    float sc = 1.0f / (sqrtf(fmaxf(var, 0.0f)) + 1e-9f);
    out[(size_t)z * 512 + t] = y0A * sc;
    out[(size_t)z * 512 + t + 64] = y0B * sc;

    float yA[3], yB[3];
    float nA = 1e-9f, nB = 1e-9f;
#pragma unroll
    for (int k = 0; k < 3; ++k) {
        yA[k] = PW0 * r0[CS * (2 + k) + t];
        yB[k] = PW0 * r0[CS * (2 + k) + t + 64];
        nA += yA[k] * yA[k];
        nB += yB[k] * yB[k];
    }
    nA = sqrtf(nA);
    nB = sqrtf(nB);
    float t1 = nA + nB, t2 = nA * nA + nB * nB;
    for (int o = 32; o; o >>= 1) {
        t1 += __shfl_xor(t1, o);
        t2 += __shfl_xor(t2, o);
    }
    float meanv = t1 * (1.0f / 128.0f);
    float varv = (t2 - 128.0f * meanv * meanv) * (1.0f / 127.0f);
    float sv = 1.0f / (sqrtf(fmaxf(varv, 0.0f)) + 1e-9f);
#pragma unroll
    for (int k = 0; k < 3; ++k) {
        out[(size_t)z * 512 + 128 + t * 3 + k] = yA[k] * sv;
        out[(size_t)z * 512 + 128 + (t + 64) * 3 + k] = yB[k] * sv;
    }
}

extern "C" void kernel_launch(void* const* d_in, const int* in_sizes, int n_in,
                              void* d_out, int out_size, void* d_ws, size_t ws_size,
                              hipStream_t stream) {
    const float* x = (const float*)d_in[0];
    const float* Wss = (const float*)d_in[1];
    const float* Wvv = (const float*)d_in[2];
    const float* Wsv = (const float*)d_in[3];
    const float* Wvs = (const float*)d_in[4];
    f16* wstream = (f16*)d_ws;
    float* raw = (float*)((char*)d_ws + RAW_OFF_BYTES);
    float* out = (float*)d_out;

    hipLaunchKernelGGL(prep_weights, dim3(384), dim3(256), 0, stream,
                       Wss, Wvv, Wsv, Wvs, wstream);
    hipLaunchKernelGGL(si_main, dim3(256), dim3(1024), 0, stream, x, wstream, raw);
    hipLaunchKernelGGL(si_finalize, dim3(NBATCH), dim3(64), 0, stream, raw, out);
}

// Round 6
// 270.459 us; speedup vs baseline: 1.5157x; 1.5157x over previous
//
#include <hip/hip_runtime.h>

// SelfInteraction on MI355X.
// R5: channel-serialized phases (block-wide ss -> vv -> cb) so per-phase B working set
// (2MB/XCD) is L2-resident; wave=(mh,nt,vb) M32xN32xKquarter; 4-step dbuf B pipeline (ss),
// 2-step dbuf (vv/cb); f16x4 batched sp reads; PSTR=130 conflict-free LDS (R4-proven).

#define C 128
#define NBATCH 8192

typedef _Float16 f16;
typedef _Float16 f16x4 __attribute__((ext_vector_type(4)));
typedef _Float16 f16x8 __attribute__((ext_vector_type(8)));
typedef float f32x16 __attribute__((ext_vector_type(16)));

// ws layout:
// [0, 12MB)  : 3 f16 weight streams (ss, vv*inv_sqrt3, comb=Wsv+Wvs^T), each 2,097,152 f16
//              frag order [h2][vb4][u128][nt2][kt2][lane64][j8]
//                <-> W[u][vb*32+kt*16+(l>>5)*8+j][h*64+nt*32+(l&31)]
// [12MB,32MB): raw channel sums f32 [5][8192][128]  (ss, vv_scaled, cb0, cb1, cb2)
#define WSTREAM_F16_PER_C (2*4*128*2*2*64*8)   // 2,097,152 f16 = 4MB
#define NSTREAM 3
#define RAW_OFF_BYTES ((size_t)NSTREAM*WSTREAM_F16_PER_C*2)  // 12 MB
#define PSTR 130               // 65 dwords/row: odd -> 1-bank shift per z-row
#define PLSZ (64*PSTR + 8)     // plane stride (f16): 4-dword skew between planes

__device__ __forceinline__ f16x8 splat8(f16 v) { return (f16x8){v, v, v, v, v, v, v, v}; }
union U16x8 { uint4 u; f16x8 h; };
__device__ __forceinline__ f16x8 as_h8(uint4 v) { U16x8 x; x.u = v; return x.h; }
__device__ __forceinline__ f32x16 mfma32(f16x8 a, f16x8 b, f32x16 c) {
    return __builtin_amdgcn_mfma_f32_32x32x16_f16(a, b, c, 0, 0, 0);
}

// ---------------- weight prep ----------------
__global__ __launch_bounds__(256) void prep_weights(
        const float* __restrict__ Wss, const float* __restrict__ Wvv,
        const float* __restrict__ Wsv, const float* __restrict__ Wvs,
        f16* __restrict__ out) {
    __shared__ float lds[128 * 130];
    int c = blockIdx.x >> 7;
    int u = blockIdx.x & 127;
    if (c == 2) {
        for (int i = threadIdx.x; i < 16384; i += 256) {
            int v = i >> 7, w = i & 127;
            lds[v * 130 + w] = Wsv[(size_t)u * 16384 + i] + Wvs[(size_t)v * 16384 + u * 128 + w];
        }
    } else {
        const float* src = (c == 0 ? Wss : Wvv) + (size_t)u * 16384;
        float sc = (c == 0) ? 1.0f : 0.57735026918962576f;
        for (int i = threadIdx.x; i < 16384; i += 256) {
            int v = i >> 7, w = i & 127;
            lds[v * 130 + w] = sc * src[i];
        }
    }
    __syncthreads();
    f16* dst = out + (size_t)c * WSTREAM_F16_PER_C;
    for (int pos = threadIdx.x; pos < 2048; pos += 256) {
        int hh = pos >> 10, vb = (pos >> 8) & 3, nt = (pos >> 7) & 1, kt = (pos >> 6) & 1;
        int l = pos & 63;
        int v0 = vb * 32 + kt * 16 + ((l >> 5) << 3);
        int w = hh * 64 + nt * 32 + (l & 31);
        f16x8 vals;
#pragma unroll
        for (int j = 0; j < 8; ++j) vals[j] = (f16)lds[(v0 + j) * 130 + w];
        size_t off = (((((size_t)(hh * 4 + vb) * 128 + u) * 2 + nt) * 2 + kt) * 64 + l) * 8;
        *(f16x8*)(dst + off) = vals;
    }
}

// 32x32 C/D tile write: row=(reg&3)+8*(reg>>2)+4*lk, col=l31
__device__ __forceinline__ void writeT32(float* __restrict__ raw, int c, int zb, int mtBase,
        int h, int ntOff, int l31, int lk, const f32x16& a, bool st) {
#pragma unroll
    for (int reg = 0; reg < 16; ++reg) {
        int row = (reg & 3) + 8 * (reg >> 2) + 4 * lk;
        int z = zb * 64 + mtBase + row;
        int ww = h * 64 + ntOff + l31;
        float* p = &raw[((size_t)c * NBATCH + z) * 128 + ww];
        if (st) *p = a[reg]; else *p += a[reg];
    }
}

// ---------------- main fused GEMM kernel ----------------
// grid 256: zb = bid>>1 (64-row z-tile), h = bid&1 (constant per XCD). 1024 thr = 16 waves.
// All phases: wave = (mh, nt, vb): M=32 (mh half), N=32 (nt half), K = vb quarter.
// Phase ss -> phase vv -> phase cb (fused 3k). Per-phase B hot-set = 2MB/XCD (L2-resident).
__global__ __launch_bounds__(1024, 4) void si_main(
        const float* __restrict__ x, const f16* __restrict__ wstream,
        float* __restrict__ raw) {
    __shared__ f16 xp[4 * PLSZ];   // [plane][z][v], plane 0=x0, 1..3=x1k, skewed planes

    int zb = blockIdx.x >> 1;
    int h = blockIdx.x & 1;
    int tid = threadIdx.x;

    for (int i = tid; i < 64 * 512; i += 1024) {
        int z = i >> 9, col = i & 511;
        f16 fv = (f16)x[(size_t)(zb * 64 + z) * 512 + col];
        if (col < 128) {
            xp[z * PSTR + col] = fv;
        } else {
            int cc = col - 128;
            int v = cc / 3, k = cc - v * 3;
            xp[(1 + k) * PLSZ + z * PSTR + v] = fv;
        }
    }
    __syncthreads();

    int lane = tid & 63, w = tid >> 6;
    int l31 = lane & 31, lk = lane >> 5;
    int mh = w >> 3, nt = (w >> 2) & 1, vb = w & 3;
    const f16* xp0 = xp;
    const int rowm = (mh * 32 + l31) * PSTR;

    // ================= phase 1: ss (4-step double-buffered B) =================
    f32x16 accS = {};
    {
        const uint4* bl = (const uint4*)(wstream + (size_t)h * (WSTREAM_F16_PER_C / 2))
                          + (size_t)vb * 32768 + nt * 128 + lane;
        f16x8 va0 = *(const f16x8*)&xp0[rowm + vb * 32 + lk * 8];
        f16x8 va1 = *(const f16x8*)&xp0[rowm + vb * 32 + 16 + lk * 8];
        uint4 Ba[4][2], Bb[4][2];
        f16x4 sa, sb;
#pragma unroll
        for (int s = 0; s < 4; ++s) { Ba[s][0] = bl[s * 256]; Ba[s][1] = bl[s * 256 + 64]; }
        sa = *(const f16x4*)&xp0[rowm];
#pragma unroll
        for (int s = 0; s < 4; ++s) { Bb[s][0] = bl[(4 + s) * 256]; Bb[s][1] = bl[(4 + s) * 256 + 64]; }
        sb = *(const f16x4*)&xp0[rowm + 4];

        for (int g = 0; g < 15; ++g) {
            int u0 = g * 8;
#pragma unroll
            for (int s = 0; s < 4; ++s) {
                f16x8 sp = splat8(sa[s]);
                accS = mfma32(sp * va0, as_h8(Ba[s][0]), accS);
                accS = mfma32(sp * va1, as_h8(Ba[s][1]), accS);
            }
#pragma unroll
            for (int s = 0; s < 4; ++s) {
                Ba[s][0] = bl[(u0 + 8 + s) * 256]; Ba[s][1] = bl[(u0 + 8 + s) * 256 + 64];
            }
            sa = *(const f16x4*)&xp0[rowm + u0 + 8];
#pragma unroll
            for (int s = 0; s < 4; ++s) {
                f16x8 sp = splat8(sb[s]);
                accS = mfma32(sp * va0, as_h8(Bb[s][0]), accS);
                accS = mfma32(sp * va1, as_h8(Bb[s][1]), accS);
            }
#pragma unroll
            for (int s = 0; s < 4; ++s) {
                Bb[s][0] = bl[(u0 + 12 + s) * 256]; Bb[s][1] = bl[(u0 + 12 + s) * 256 + 64];
            }
            sb = *(const f16x4*)&xp0[rowm + u0 + 12];
        }
        // epilogue: blocks 30 (Ba) and 31 (Bb)
#pragma unroll
        for (int s = 0; s < 4; ++s) {
            f16x8 sp = splat8(sa[s]);
            accS = mfma32(sp * va0, as_h8(Ba[s][0]), accS);
            accS = mfma32(sp * va1, as_h8(Ba[s][1]), accS);
        }
#pragma unroll
        for (int s = 0; s < 4; ++s) {
            f16x8 sp = splat8(sb[s]);
            accS = mfma32(sp * va0, as_h8(Bb[s][0]), accS);
            accS = mfma32(sp * va1, as_h8(Bb[s][1]), accS);
        }
    }
#pragma unroll
    for (int r = 0; r < 4; ++r) {
        __threadfence_block();
        __syncthreads();
        if (vb == r) writeT32(raw, 0, zb, mh * 32, h, nt * 32, l31, lk, accS, r == 0);
    }

    // ================= phase 2: vv (2-step dbuf, 3-plane A build) =================
    f32x16 accV = {};
    {
        const uint4* bl = (const uint4*)(wstream + WSTREAM_F16_PER_C
                          + (size_t)h * (WSTREAM_F16_PER_C / 2))
                          + (size_t)vb * 32768 + nt * 128 + lane;
        f16x8 wa0[3], wa1[3];
#pragma unroll
        for (int p = 0; p < 3; ++p) {
            wa0[p] = *(const f16x8*)&xp[(1 + p) * PLSZ + rowm + vb * 32 + lk * 8];
            wa1[p] = *(const f16x8*)&xp[(1 + p) * PLSZ + rowm + vb * 32 + 16 + lk * 8];
        }
        uint4 Ba[2][2], Bb[2][2];
        f16x4 s0a, s1a, s2a, s0n, s1n, s2n;
#pragma unroll
        for (int s = 0; s < 2; ++s) { Ba[s][0] = bl[s * 256]; Ba[s][1] = bl[s * 256 + 64]; }
#pragma unroll
        for (int s = 0; s < 2; ++s) { Bb[s][0] = bl[(2 + s) * 256]; Bb[s][1] = bl[(2 + s) * 256 + 64]; }
        s0a = *(const f16x4*)&xp[1 * PLSZ + rowm];
        s1a = *(const f16x4*)&xp[2 * PLSZ + rowm];
        s2a = *(const f16x4*)&xp[3 * PLSZ + rowm];

        for (int g = 0; g < 31; ++g) {
            int u0 = g * 4;
#pragma unroll
            for (int s = 0; s < 2; ++s) {
                f16x8 p0 = splat8(s0a[s]), p1 = splat8(s1a[s]), p2 = splat8(s2a[s]);
                f16x8 A0 = p0 * wa0[0] + p1 * wa0[1] + p2 * wa0[2];
                f16x8 A1 = p0 * wa1[0] + p1 * wa1[1] + p2 * wa1[2];
                accV = mfma32(A0, as_h8(Ba[s][0]), accV);
                accV = mfma32(A1, as_h8(Ba[s][1]), accV);
            }
#pragma unroll
            for (int s = 0; s < 2; ++s) {
                Ba[s][0] = bl[(u0 + 4 + s) * 256]; Ba[s][1] = bl[(u0 + 4 + s) * 256 + 64];
            }
            s0n = *(const f16x4*)&xp[1 * PLSZ + rowm + u0 + 4];
            s1n = *(const f16x4*)&xp[2 * PLSZ + rowm + u0 + 4];
            s2n = *(const f16x4*)&xp[3 * PLSZ + rowm + u0 + 4];
#pragma unroll
            for (int s = 0; s < 2; ++s) {
                f16x8 p0 = splat8(s0a[s + 2]), p1 = splat8(s1a[s + 2]), p2 = splat8(s2a[s + 2]);
                f16x8 A0 = p0 * wa0[0] + p1 * wa0[1] + p2 * wa0[2];
                f16x8 A1 = p0 * wa1[0] + p1 * wa1[1] + p2 * wa1[2];
                accV = mfma32(A0, as_h8(Bb[s][0]), accV);
                accV = mfma32(A1, as_h8(Bb[s][1]), accV);
            }
#pragma unroll
            for (int s = 0; s < 2; ++s) {
                Bb[s][0] = bl[(u0 + 6 + s) * 256]; Bb[s][1] = bl[(u0 + 6 + s) * 256 + 64];
            }
            s0a = s0n; s1a = s1n; s2a = s2n;
        }
        // epilogue: steps 124..127
#pragma unroll
        for (int s = 0; s < 2; ++s) {
            f16x8 p0 = splat8(s0a[s]), p1 = splat8(s1a[s]), p2 = splat8(s2a[s]);
            f16x8 A0 = p0 * wa0[0] + p1 * wa0[1] + p2 * wa0[2];
            f16x8 A1 = p0 * wa1[0] + p1 * wa1[1] + p2 * wa1[2];
            accV = mfma32(A0, as_h8(Ba[s][0]), accV);
            accV = mfma32(A1, as_h8(Ba[s][1]), accV);
        }
#pragma unroll
        for (int s = 0; s < 2; ++s) {
            f16x8 p0 = splat8(s0a[s + 2]), p1 = splat8(s1a[s + 2]), p2 = splat8(s2a[s + 2]);
            f16x8 A0 = p0 * wa0[0] + p1 * wa0[1] + p2 * wa0[2];
            f16x8 A1 = p0 * wa1[0] + p1 * wa1[1] + p2 * wa1[2];
            accV = mfma32(A0, as_h8(Bb[s][0]), accV);
            accV = mfma32(A1, as_h8(Bb[s][1]), accV);
        }
    }
#pragma unroll
    for (int r = 0; r < 4; ++r) {
        __threadfence_block();
        __syncthreads();
        if (vb == r) writeT32(raw, 1, zb, mh * 32, h, nt * 32, l31, lk, accV, r == 0);
    }

    // ================= phase 3: cb fused (3 k per B-load, 2-step dbuf) =================
    f32x16 acc2[3] = {};
    {
        const uint4* bl = (const uint4*)(wstream + (size_t)2 * WSTREAM_F16_PER_C
                          + (size_t)h * (WSTREAM_F16_PER_C / 2))
                          + (size_t)vb * 32768 + nt * 128 + lane;
        f16x8 wb0[3], wb1[3];
#pragma unroll
        for (int p = 0; p < 3; ++p) {
            wb0[p] = *(const f16x8*)&xp[(1 + p) * PLSZ + rowm + vb * 32 + lk * 8];
            wb1[p] = *(const f16x8*)&xp[(1 + p) * PLSZ + rowm + vb * 32 + 16 + lk * 8];
        }
        uint4 Ba[2][2], Bb[2][2];
        f16x4 sa, sn;
#pragma unroll
        for (int s = 0; s < 2; ++s) { Ba[s][0] = bl[s * 256]; Ba[s][1] = bl[s * 256 + 64]; }
#pragma unroll
        for (int s = 0; s < 2; ++s) { Bb[s][0] = bl[(2 + s) * 256]; Bb[s][1] = bl[(2 + s) * 256 + 64]; }
        sa = *(const f16x4*)&xp0[rowm];

        for (int g = 0; g < 31; ++g) {
            int u0 = g * 4;
#pragma unroll
            for (int s = 0; s < 2; ++s) {
                f16x8 sp = splat8(sa[s]);
                acc2[0] = mfma32(sp * wb0[0], as_h8(Ba[s][0]), acc2[0]);
                acc2[0] = mfma32(sp * wb1[0], as_h8(Ba[s][1]), acc2[0]);
                acc2[1] = mfma32(sp * wb0[1], as_h8(Ba[s][0]), acc2[1]);
                acc2[1] = mfma32(sp * wb1[1], as_h8(Ba[s][1]), acc2[1]);
                acc2[2] = mfma32(sp * wb0[2], as_h8(Ba[s][0]), acc2[2]);
                acc2[2] = mfma32(sp * wb1[2], as_h8(Ba[s][1]), acc2[2]);
            }
#pragma unroll
            for (int s = 0; s < 2; ++s) {
                Ba[s][0] = bl[(u0 + 4 + s) * 256]; Ba[s][1] = bl[(u0 + 4 + s) * 256 + 64];
            }
            sn = *(const f16x4*)&xp0[rowm + u0 + 4];
#pragma unroll
            for (int s = 0; s < 2; ++s) {
                f16x8 sp = splat8(sa[s + 2]);
                acc2[0] = mfma32(sp * wb0[0], as_h8(Bb[s][0]), acc2[0]);
                acc2[0] = mfma32(sp * wb1[0], as_h8(Bb[s][1]), acc2[0]);
                acc2[1] = mfma32(sp * wb0[1], as_h8(Bb[s][0]), acc2[1]);
                acc2[1] = mfma32(sp * wb1[1], as_h8(Bb[s][1]), acc2[1]);
                acc2[2] = mfma32(sp * wb0[2], as_h8(Bb[s][0]), acc2[2]);
                acc2[2] = mfma32(sp * wb1[2], as_h8(Bb[s][1]), acc2[2]);
            }
#pragma unroll
            for (int s = 0; s < 2; ++s) {
                Bb[s][0] = bl[(u0 + 6 + s) * 256]; Bb[s][1] = bl[(u0 + 6 + s) * 256 + 64];
            }
            sa = sn;
        }
        // epilogue: steps 124..127
#pragma unroll
        for (int s = 0; s < 2; ++s) {
            f16x8 sp = splat8(sa[s]);
            acc2[0] = mfma32(sp * wb0[0], as_h8(Ba[s][0]), acc2[0]);
            acc2[0] = mfma32(sp * wb1[0], as_h8(Ba[s][1]), acc2[0]);
            acc2[1] = mfma32(sp * wb0[1], as_h8(Ba[s][0]), acc2[1]);
            acc2[1] = mfma32(sp * wb1[1], as_h8(Ba[s][1]), acc2[1]);
            acc2[2] = mfma32(sp * wb0[2], as_h8(Ba[s][0]), acc2[2]);
            acc2[2] = mfma32(sp * wb1[2], as_h8(Ba[s][1]), acc2[2]);
        }
#pragma unroll
        for (int s = 0; s < 2; ++s) {
            f16x8 sp = splat8(sa[s + 2]);
            acc2[0] = mfma32(sp * wb0[0], as_h8(Bb[s][0]), acc2[0]);
            acc2[0] = mfma32(sp * wb1[0], as_h8(Bb[s][1]), acc2[0]);
            acc2[1] = mfma32(sp * wb0[1], as_h8(Bb[s][0]), acc2[1]);
            acc2[1] = mfma32(sp * wb1[1], as_h8(Bb[s][1]), acc2[1]);
            acc2[2] = mfma32(sp * wb0[2], as_h8(Bb[s][0]), acc2[2]);
            acc2[2] = mfma32(sp * wb1[2], as_h8(Bb[s][1]), acc2[2]);
        }
    }
    // cb reduce: rotated k rounds; wave writes channel 2+k (k=(vb-r)&3, k<3) tile (mh,nt)
#pragma unroll
    for (int r = 0; r < 4; ++r) {
        __threadfence_block();
        __syncthreads();
        int k = (vb - r) & 3;
        if (k == 0)      writeT32(raw, 2, zb, mh * 32, h, nt * 32, l31, lk, acc2[0], r == 0);
        else if (k == 1) writeT32(raw, 3, zb, mh * 32, h, nt * 32, l31, lk, acc2[1], r == 0);
        else if (k == 2) writeT32(raw, 4, zb, mh * 32, h, nt * 32, l31, lk, acc2[2], r == 0);
    }
}

// ---------------- finalize ----------------
__global__ __launch_bounds__(64) void si_finalize(const float* __restrict__ raw,
                                                  float* __restrict__ out) {
    const float PW0 = 0.0055242717280199f;   // 1/sqrt(2*128*128) == pw1/sqrt(3)
    int z = blockIdx.x;
    int t = threadIdx.x;
    const size_t CS = (size_t)NBATCH * 128;
    const float* r0 = raw + (size_t)z * 128;

    float y0A = PW0 * (r0[t] + r0[CS + t]);
    float y0B = PW0 * (r0[t + 64] + r0[CS + t + 64]);
    float s1 = y0A + y0B, s2 = y0A * y0A + y0B * y0B;
    for (int o = 32; o; o >>= 1) {
        s1 += __shfl_xor(s1, o);
        s2 += __shfl_xor(s2, o);
    }
    float mean = s1 * (1.0f / 128.0f);
    float var = (s2 - 128.0f * mean * mean) * (1.0f / 127.0f);
    float sc = 1.0f / (sqrtf(fmaxf(var, 0.0f)) + 1e-9f);
    out[(size_t)z * 512 + t] = y0A * sc;
    out[(size_t)z * 512 + t + 64] = y0B * sc;

    float yA[3], yB[3];
    float nA = 1e-9f, nB = 1e-9f;
#pragma unroll
    for (int k = 0; k < 3; ++k) {
        yA[k] = PW0 * r0[CS * (2 + k) + t];
        yB[k] = PW0 * r0[CS * (2 + k) + t + 64];
        nA += yA[k] * yA[k];
        nB += yB[k] * yB[k];
    }
    nA = sqrtf(nA);
    nB = sqrtf(nB);
    float t1 = nA + nB, t2 = nA * nA + nB * nB;
    for (int o = 32; o; o >>= 1) {
        t1 += __shfl_xor(t1, o);
        t2 += __shfl_xor(t2, o);
    }
    float meanv = t1 * (1.0f / 128.0f);
    float varv = (t2 - 128.0f * meanv * meanv) * (1.0f / 127.0f);
    float sv = 1.0f / (sqrtf(fmaxf(varv, 0.0f)) + 1e-9f);
#pragma unroll
    for (int k = 0; k < 3; ++k) {
        out[(size_t)z * 512 + 128 + t * 3 + k] = yA[k] * sv;
        out[(size_t)z * 512 + 128 + (t + 64) * 3 + k] = yB[k] * sv;
    }
}

extern "C" void kernel_launch(void* const* d_in, const int* in_sizes, int n_in,
                              void* d_out, int out_size, void* d_ws, size_t ws_size,
                              hipStream_t stream) {
    const float* x = (const float*)d_in[0];
    const float* Wss = (const float*)d_in[1];
    const float* Wvv = (const float*)d_in[2];
    const float* Wsv = (const float*)d_in[3];
    const float* Wvs = (const float*)d_in[4];
    f16* wstream = (f16*)d_ws;
    float* raw = (float*)((char*)d_ws + RAW_OFF_BYTES);
    float* out = (float*)d_out;

    hipLaunchKernelGGL(prep_weights, dim3(384), dim3(256), 0, stream,
                       Wss, Wvv, Wsv, Wvs, wstream);
    hipLaunchKernelGGL(si_main, dim3(256), dim3(1024), 0, stream, x, wstream, raw);
    hipLaunchKernelGGL(si_finalize, dim3(NBATCH), dim3(64), 0, stream, raw, out);
}

// Round 7
// 257.524 us; speedup vs baseline: 1.5919x; 1.0502x over previous
//
#include <hip/hip_runtime.h>

// SelfInteraction on MI355X.
// R6: B through LDS via global_load_lds (16B), u-step-major stream layout
// ([h][u][vb][nt][kt][lane][j]), 2-u-step chunks double-buffered with one barrier
// per chunk, ds_read_b128 consume with in-wave B reuse (M=64 ss/vv, 3k-fused cb).

#define C 128
#define NBATCH 8192

typedef _Float16 f16;
typedef _Float16 f16x8 __attribute__((ext_vector_type(8)));
typedef float f32x16 __attribute__((ext_vector_type(16)));
typedef unsigned int u32;

// ws layout:
// [0, 12MB)  : 3 f16 weight streams (ss, vv*inv_sqrt3, comb=Wsv+Wvs^T), each 2,097,152 f16
//              order [h2][u128][vb4][nt2][kt2][lane64][j8]
//                <-> W[u][vb*32+kt*16+(l>>5)*8+j][h*64+nt*32+(l&31)]
// [12MB,32MB): raw channel sums f32 [5][8192][128]  (ss, vv_scaled, cb0, cb1, cb2)
#define HALFSTREAM 1048576                    // f16 per h-half (2 MB)
#define WSTREAM_F16_PER_C (2*HALFSTREAM)      // 4 MB per stream
#define NSTREAM 3
#define RAW_OFF_BYTES ((size_t)NSTREAM*WSTREAM_F16_PER_C*2)  // 12 MB
#define PSTR 130               // 65 dwords/row: odd -> 1-bank shift per z-row
#define PLSZ (64*PSTR + 8)     // x-plane stride (f16), 4-dword inter-plane skew

__device__ __forceinline__ f16x8 splat8(f16 v) { return (f16x8){v, v, v, v, v, v, v, v}; }
__device__ __forceinline__ f32x16 mfma32(f16x8 a, f16x8 b, f32x16 c) {
    return __builtin_amdgcn_mfma_f32_32x32x16_f16(a, b, c, 0, 0, 0);
}
__device__ __forceinline__ void gl_lds16(const f16* g, f16* l) {
    __builtin_amdgcn_global_load_lds(
        (const __attribute__((address_space(1))) u32*)g,
        (__attribute__((address_space(3))) u32*)l, 16, 0, 0);
}

// ---------------- weight prep ----------------
// grid 384: c = blockIdx>>7 (0=ss, 1=vv*inv_sqrt3, 2=Wsv+Wvs^T), u = blockIdx&127
__global__ __launch_bounds__(256) void prep_weights(
        const float* __restrict__ Wss, const float* __restrict__ Wvv,
        const float* __restrict__ Wsv, const float* __restrict__ Wvs,
        f16* __restrict__ out) {
    __shared__ float lds[128 * 130];
    int c = blockIdx.x >> 7;
    int u = blockIdx.x & 127;
    if (c == 2) {
        for (int i = threadIdx.x; i < 16384; i += 256) {
            int v = i >> 7, w = i & 127;
            lds[v * 130 + w] = Wsv[(size_t)u * 16384 + i] + Wvs[(size_t)v * 16384 + u * 128 + w];
        }
    } else {
        const float* src = (c == 0 ? Wss : Wvv) + (size_t)u * 16384;
        float sc = (c == 0) ? 1.0f : 0.57735026918962576f;
        for (int i = threadIdx.x; i < 16384; i += 256) {
            int v = i >> 7, w = i & 127;
            lds[v * 130 + w] = sc * src[i];
        }
    }
    __syncthreads();
    f16* dst = out + (size_t)c * WSTREAM_F16_PER_C;
    for (int pos = threadIdx.x; pos < 2048; pos += 256) {
        int hh = pos >> 10;
        int r = pos & 1023;
        int vb = r >> 8, nt = (r >> 7) & 1, kt = (r >> 6) & 1, l = r & 63;
        int v0 = vb * 32 + kt * 16 + ((l >> 5) << 3);
        int w = hh * 64 + nt * 32 + (l & 31);
        f16x8 vals;
#pragma unroll
        for (int j = 0; j < 8; ++j) vals[j] = (f16)lds[(v0 + j) * 130 + w];
        size_t off = (size_t)hh * HALFSTREAM + (size_t)u * 8192
                   + (size_t)(((vb * 2 + nt) * 2 + kt)) * 512 + (size_t)l * 8;
        *(f16x8*)(dst + off) = vals;
    }
}

// 32x32 C/D tile write: row=(reg&3)+8*(reg>>2)+4*lk, col=l31
__device__ __forceinline__ void writeT32(float* __restrict__ raw, int c, int zb, int mtBase,
        int h, int ntOff, int l31, int lk, const f32x16& a, bool st) {
#pragma unroll
    for (int reg = 0; reg < 16; ++reg) {
        int row = (reg & 3) + 8 * (reg >> 2) + 4 * lk;
        int z = zb * 64 + mtBase + row;
        int ww = h * 64 + ntOff + l31;
        float* p = &raw[((size_t)c * NBATCH + z) * 128 + ww];
        if (st) *p = a[reg]; else *p += a[reg];
    }
}

// ---------------- main fused GEMM kernel ----------------
// grid 256: zb = bid>>1 (64-row z-tile), h = bid&1 (XCD-constant). 1024 thr = 16 waves.
// B staged per u-step (16 KB) into LDS dbuf, chunks of 2 u-steps, 1 barrier/chunk.
// ss/vv: wave=(nt2,vb4,kt2), M=64 (2 mg tiles), 1 B-frag -> 2 MFMA, 8 reduce rounds.
// cb:    wave=(mg2,nt2,vb4), 2 B-frags -> 6 MFMA (3k fused), 4 rotated reduce rounds.
__global__ __launch_bounds__(1024, 4) void si_main(
        const float* __restrict__ x, const f16* __restrict__ wstream,
        float* __restrict__ raw) {
    __shared__ f16 xp[4 * PLSZ];        // x planes [plane][z][v], ~67 KB
    __shared__ f16 bst[2 * 16384];      // B dbuf: [buf2][ul2][8192 f16], 64 KB

    int zb = blockIdx.x >> 1;
    int h = blockIdx.x & 1;
    int tid = threadIdx.x;

    const f16* sA = wstream + (size_t)h * HALFSTREAM;                           // ss
    const f16* sB = wstream + WSTREAM_F16_PER_C + (size_t)h * HALFSTREAM;       // vv
    const f16* sC = wstream + (size_t)2 * WSTREAM_F16_PER_C + (size_t)h * HALFSTREAM; // cb

    // stage x tile into LDS planes
    for (int i = tid; i < 64 * 512; i += 1024) {
        int z = i >> 9, col = i & 511;
        f16 fv = (f16)x[(size_t)(zb * 64 + z) * 512 + col];
        if (col < 128) {
            xp[z * PSTR + col] = fv;
        } else {
            int cc = col - 128;
            int v = cc / 3, k = cc - v * 3;
            xp[(1 + k) * PLSZ + z * PSTR + v] = fv;
        }
    }
    // prologue: stage ss chunk 0 (u=0,1)
    gl_lds16(sA + tid * 8, &bst[tid * 8]);
    gl_lds16(sA + 8192 + tid * 8, &bst[8192 + tid * 8]);
    __syncthreads();

    int lane = tid & 63, w = tid >> 6;
    int l31 = lane & 31, lk = lane >> 5;
    const int rm0 = l31 * PSTR, rm1 = (32 + l31) * PSTR;

    // ================= phase 1: ss =================
    int nt = w >> 3, vb = (w >> 1) & 3, kt = w & 1;
    int segF = ((vb * 2 + nt) * 2 + kt) * 512 + lane * 8;   // f16 offset of wave's frag
    f32x16 accA = {}, accB = {};
    {
        f16x8 va0 = *(const f16x8*)&xp[rm0 + vb * 32 + kt * 16 + lk * 8];
        f16x8 va1 = *(const f16x8*)&xp[rm1 + vb * 32 + kt * 16 + lk * 8];
        for (int c = 0; c < 64; ++c) {
            int cur = (c & 1) * 16384;
            if (c < 63) {
                const f16* g = sA + (size_t)(c + 1) * 16384 + tid * 8;
                f16* d = &bst[(~c & 1) * 16384 + tid * 8];
                gl_lds16(g, d);
                gl_lds16(g + 8192, d + 8192);
            }
#pragma unroll
            for (int ul = 0; ul < 2; ++ul) {
                int u = c * 2 + ul;
                f16x8 bf = *(const f16x8*)&bst[cur + ul * 8192 + segF];
                f16 sp0 = xp[rm0 + u], sp1 = xp[rm1 + u];
                accA = mfma32(splat8(sp0) * va0, bf, accA);
                accB = mfma32(splat8(sp1) * va1, bf, accB);
            }
            __syncthreads();
        }
    }
    // prefetch vv chunk 0 (lands during reduce barriers); bst[0] free (last compute used buf1)
    gl_lds16(sB + tid * 8, &bst[tid * 8]);
    gl_lds16(sB + 8192 + tid * 8, &bst[8192 + tid * 8]);
    // ss reduce: 8 rounds, key = w&7
#pragma unroll
    for (int r = 0; r < 8; ++r) {
        __threadfence_block();
        __syncthreads();
        if ((w & 7) == r) {
            writeT32(raw, 0, zb, 0,  h, nt * 32, l31, lk, accA, r == 0);
            writeT32(raw, 0, zb, 32, h, nt * 32, l31, lk, accB, r == 0);
        }
    }
    __syncthreads();

    // ================= phase 2: vv =================
    f32x16 accVA = {}, accVB = {};
    {
        f16x8 wa0[3], wa1[3];
#pragma unroll
        for (int p = 0; p < 3; ++p) {
            wa0[p] = *(const f16x8*)&xp[(1 + p) * PLSZ + rm0 + vb * 32 + kt * 16 + lk * 8];
            wa1[p] = *(const f16x8*)&xp[(1 + p) * PLSZ + rm1 + vb * 32 + kt * 16 + lk * 8];
        }
        for (int c = 0; c < 64; ++c) {
            int cur = (c & 1) * 16384;
            if (c < 63) {
                const f16* g = sB + (size_t)(c + 1) * 16384 + tid * 8;
                f16* d = &bst[(~c & 1) * 16384 + tid * 8];
                gl_lds16(g, d);
                gl_lds16(g + 8192, d + 8192);
            }
#pragma unroll
            for (int ul = 0; ul < 2; ++ul) {
                int u = c * 2 + ul;
                f16x8 bf = *(const f16x8*)&bst[cur + ul * 8192 + segF];
                f16x8 A0 = splat8(xp[1 * PLSZ + rm0 + u]) * wa0[0]
                         + splat8(xp[2 * PLSZ + rm0 + u]) * wa0[1]
                         + splat8(xp[3 * PLSZ + rm0 + u]) * wa0[2];
                f16x8 A1 = splat8(xp[1 * PLSZ + rm1 + u]) * wa1[0]
                         + splat8(xp[2 * PLSZ + rm1 + u]) * wa1[1]
                         + splat8(xp[3 * PLSZ + rm1 + u]) * wa1[2];
                accVA = mfma32(A0, bf, accVA);
                accVB = mfma32(A1, bf, accVB);
            }
            __syncthreads();
        }
    }
    // prefetch cb chunk 0
    gl_lds16(sC + tid * 8, &bst[tid * 8]);
    gl_lds16(sC + 8192 + tid * 8, &bst[8192 + tid * 8]);
    // vv reduce: 8 rounds
#pragma unroll
    for (int r = 0; r < 8; ++r) {
        __threadfence_block();
        __syncthreads();
        if ((w & 7) == r) {
            writeT32(raw, 1, zb, 0,  h, nt * 32, l31, lk, accVA, r == 0);
            writeT32(raw, 1, zb, 32, h, nt * 32, l31, lk, accVB, r == 0);
        }
    }
    __syncthreads();

    // ================= phase 3: cb (3k fused) =================
    int mg = w >> 3, ntc = (w >> 2) & 1, vbc = w & 3;
    int seg0 = ((vbc * 2 + ntc) * 2) * 512 + lane * 8;   // kt=0 frag
    f32x16 acc2[3] = {};
    {
        const int rowm = (mg * 32 + l31) * PSTR;
        f16x8 vvb[3][2];
#pragma unroll
        for (int p = 0; p < 3; ++p)
#pragma unroll
            for (int tt = 0; tt < 2; ++tt)
                vvb[p][tt] = *(const f16x8*)&xp[(1 + p) * PLSZ + rowm
                                                + vbc * 32 + tt * 16 + lk * 8];
        for (int c = 0; c < 64; ++c) {
            int cur = (c & 1) * 16384;
            if (c < 63) {
                const f16* g = sC + (size_t)(c + 1) * 16384 + tid * 8;
                f16* d = &bst[(~c & 1) * 16384 + tid * 8];
                gl_lds16(g, d);
                gl_lds16(g + 8192, d + 8192);
            }
#pragma unroll
            for (int ul = 0; ul < 2; ++ul) {
                int u = c * 2 + ul;
                f16x8 b0 = *(const f16x8*)&bst[cur + ul * 8192 + seg0];
                f16x8 b1 = *(const f16x8*)&bst[cur + ul * 8192 + seg0 + 512];
                f16x8 sp = splat8(xp[rowm + u]);
#pragma unroll
                for (int k = 0; k < 3; ++k) {
                    acc2[k] = mfma32(sp * vvb[k][0], b0, acc2[k]);
                    acc2[k] = mfma32(sp * vvb[k][1], b1, acc2[k]);
                }
            }
            __syncthreads();
        }
    }
    // cb reduce: 4 rotated rounds, key vbc
#pragma unroll
    for (int r = 0; r < 4; ++r) {
        __threadfence_block();
        __syncthreads();
        int k = (vbc - r) & 3;
        if (k == 0)      writeT32(raw, 2, zb, mg * 32, h, ntc * 32, l31, lk, acc2[0], r == 0);
        else if (k == 1) writeT32(raw, 3, zb, mg * 32, h, ntc * 32, l31, lk, acc2[1], r == 0);
        else if (k == 2) writeT32(raw, 4, zb, mg * 32, h, ntc * 32, l31, lk, acc2[2], r == 0);
    }
}

// ---------------- finalize ----------------
__global__ __launch_bounds__(64) void si_finalize(const float* __restrict__ raw,
                                                  float* __restrict__ out) {
    const float PW0 = 0.0055242717280199f;   // 1/sqrt(2*128*128) == pw1/sqrt(3)
    int z = blockIdx.x;
    int t = threadIdx.x;
    const size_t CS = (size_t)NBATCH * 128;
    const float* r0 = raw + (size_t)z * 128;

    float y0A = PW0 * (r0[t] + r0[CS + t]);
    float y0B = PW0 * (r0[t + 64] + r0[CS + t + 64]);
    float s1 = y0A + y0B, s2 = y0A * y0A + y0B * y0B;
    for (int o = 32; o; o >>= 1) {
        s1 += __shfl_xor(s1, o);
        s2 += __shfl_xor(s2, o);
    }
    float mean = s1 * (1.0f / 128.0f);
    float var = (s2 - 128.0f * mean * mean) * (1.0f / 127.0f);
    float sc = 1.0f / (sqrtf(fmaxf(var, 0.0f)) + 1e-9f);
    out[(size_t)z * 512 + t] = y0A * sc;
    out[(size_t)z * 512 + t + 64] = y0B * sc;

    float yA[3], yB[3];
    float nA = 1e-9f, nB = 1e-9f;
#pragma unroll
    for (int k = 0; k < 3; ++k) {
        yA[k] = PW0 * r0[CS * (2 + k) + t];
        yB[k] = PW0 * r0[CS * (2 + k) + t + 64];
        nA += yA[k] * yA[k];
        nB += yB[k] * yB[k];
    }
    nA = sqrtf(nA);
    nB = sqrtf(nB);
    float t1 = nA + nB, t2 = nA * nA + nB * nB;
    for (int o = 32; o; o >>= 1) {
        t1 += __shfl_xor(t1, o);
        t2 += __shfl_xor(t2, o);
    }
    float meanv = t1 * (1.0f / 128.0f);
    float varv = (t2 - 128.0f * meanv * meanv) * (1.0f / 127.0f);
    float sv = 1.0f / (sqrtf(fmaxf(varv, 0.0f)) + 1e-9f);
#pragma unroll
    for (int k = 0; k < 3; ++k) {
        out[(size_t)z * 512 + 128 + t * 3 + k] = yA[k] * sv;
        out[(size_t)z * 512 + 128 + (t + 64) * 3 + k] = yB[k] * sv;
    }
}

extern "C" void kernel_launch(void* const* d_in, const int* in_sizes, int n_in,
                              void* d_out, int out_size, void* d_ws, size_t ws_size,
                              hipStream_t stream) {
    const float* x = (const float*)d_in[0];
    const float* Wss = (const float*)d_in[1];
    const float* Wvv = (const float*)d_in[2];
    const float* Wsv = (const float*)d_in[3];
    const float* Wvs = (const float*)d_in[4];
    f16* wstream = (f16*)d_ws;
    float* raw = (float*)((char*)d_ws + RAW_OFF_BYTES);
    float* out = (float*)d_out;

    hipLaunchKernelGGL(prep_weights, dim3(384), dim3(256), 0, stream,
                       Wss, Wvv, Wsv, Wvs, wstream);
    hipLaunchKernelGGL(si_main, dim3(256), dim3(1024), 0, stream, x, wstream, raw);
    hipLaunchKernelGGL(si_finalize, dim3(NBATCH), dim3(64), 0, stream, raw, out);
}